// Round 4
// baseline (134.893 us; speedup 1.0000x reference)
//
#include <hip/hip_runtime.h>

// ---------------- compile-time constants / tables ----------------
constexpr int NRBF = 8;   // radial basis functions
constexpr int NA   = 20;  // angular monomials (MAX_L=3)
constexpr int NC   = 9;   // edge channels (n_emb^2)
constexpr int EDW  = 64;  // per-edge record: 32 rad2 + 20 ang + 9 enc + 3 pad
constexpr int CAP  = 64;  // per-node edge bucket capacity (deg~Poisson(6))

// monomial exponent tables, index order matches reference _lxlylz_list(3)
__constant__ int cLX[NA] = {0,1,0,0,2,1,1,0,0,0,3,2,2,1,1,1,0,0,0,0};
__constant__ int cLY[NA] = {0,0,1,0,0,1,0,2,1,0,0,1,0,2,1,0,3,2,1,0};
__constant__ int cLZ[NA] = {0,0,0,1,0,0,1,0,1,2,0,0,1,0,1,2,0,1,2,3};
__constant__ int cLOF[NA]= {0,1,1,1,2,2,2,2,2,2,3,3,3,3,3,3,3,3,3,3};

__device__ __forceinline__ int zmap(int z) {
    return z == 1 ? 0 : (z == 6 ? 1 : (z == 7 ? 2 : 3));
}

// ---------------- nu=3 term table (constexpr-generated) ----------------
struct Nu3Tbl {
    int n;
    unsigned char i1[200], i2[200], i3[200], cb[200];
    float pref[200];
};
constexpr int idx_of(int lx, int ly, int lz) {
    int l = lx + ly + lz;
    int base = (l == 0) ? 0 : ((l == 1) ? 1 : ((l == 2) ? 4 : 10));
    int d = l - lx;
    return base + d * (d + 1) / 2 + (d - ly);
}
constexpr int factc(int k) { return k <= 1 ? 1 : k * factc(k - 1); }
constexpr float multinom(int lx, int ly, int lz) {
    return (float)(factc(lx + ly + lz) / (factc(lx) * factc(ly) * factc(lz)));
}
constexpr Nu3Tbl make_nu3() {
    Nu3Tbl t{};
    const int combos[4][3] = {{1,1,1},{1,1,2},{1,2,1},{2,1,1}};
    for (int q = 0; q < 4; ++q) {
        int e12 = combos[q][0], e13 = combos[q][1], e23 = combos[q][2];
        for (int ax = e12; ax >= 0; --ax) for (int ay = e12-ax; ay >= 0; --ay) { int az = e12-ax-ay;
        for (int bx = e13; bx >= 0; --bx) for (int by = e13-bx; by >= 0; --by) { int bz = e13-bx-by;
        for (int cx = e23; cx >= 0; --cx) for (int cy = e23-cx; cy >= 0; --cy) { int cz = e23-cx-cy;
            t.i1[t.n] = (unsigned char)idx_of(ax+bx, ay+by, az+bz);
            t.i2[t.n] = (unsigned char)idx_of(ax+cx, ay+cy, az+cz);
            t.i3[t.n] = (unsigned char)idx_of(bx+cx, by+cy, bz+cz);
            t.cb[t.n] = (unsigned char)q;
            t.pref[t.n] = multinom(ax,ay,az) * multinom(bx,by,bz) * multinom(cx,cy,cz);
            t.n++;
        }}}
    }
    return t;
}
constexpr Nu3Tbl NU3 = make_nu3();

// ---------------- kernel 1: per-edge compact record + direct bucketing ----------------
// 4 edges per 256-thread block (one wave64 per edge).
__global__ __launch_bounds__(256) void precompute_kernel(
    const float* __restrict__ pos, const float* __restrict__ shifts,
    const float* __restrict__ embW, const float* __restrict__ radW,
    const int* __restrict__ zs, const int* __restrict__ eidx,
    float* __restrict__ edata, int* __restrict__ counts, int* __restrict__ order,
    int E)
{
    __shared__ float s_rad[4][NRBF];
    int w = threadIdx.x >> 6;
    int lane = threadIdx.x & 63;
    int e = blockIdx.x * 4 + w;
    bool valid = (e < E);

    int snd = 0, rcv = 0;
    float dx = 0.f, dy = 0.f, dz = 0.f, len = 1.f;
    if (valid) {
        snd = eidx[e]; rcv = eidx[E + e];
        dx = pos[rcv*3+0] - pos[snd*3+0] + shifts[e*3+0];
        dy = pos[rcv*3+1] - pos[snd*3+1] + shifts[e*3+1];
        dz = pos[rcv*3+2] - pos[snd*3+2] + shifts[e*3+2];
        len = fmaxf(sqrtf(dx*dx + dy*dy + dz*dz), 1e-9f);
    }
    if (valid && lane < 8) {
        // Bessel RBF * polynomial cutoff (p=6): fc = 1 - 28 x^6 + 48 x^7 - 21 x^8
        float x = len * (1.0f / 5.5f);
        float fc = 0.f;
        if (x < 1.f) {
            float x2 = x * x, x6 = x2 * x2 * x2;
            fc = 1.f - 28.f * x6 + 48.f * x6 * x - 21.f * x6 * x2;
        }
        float rbf = 0.60302268915552724f *
                    sinf((float)(lane + 1) * 3.14159265358979323846f * len / 5.5f) / len;
        s_rad[w][lane] = rbf * fc;
    }
    __syncthreads();
    if (valid) {
        float v = 0.f;
        if (lane < 32) {                       // rad2[l][s] = sum_r W[l,r,s] * radial[r]
            int l = lane >> 3, s = lane & 7;
            float acc = 0.f;
            #pragma unroll
            for (int r = 0; r < 8; ++r) acc += radW[(l * 8 + r) * 8 + s] * s_rad[w][r];
            v = acc;
        } else if (lane < 52) {                // angular monomials
            int a = lane - 32;
            float inv = 1.f / len;
            float ux = dx * inv, uy = dy * inv, uz = dz * inv;
            float t = 1.f;
            for (int k = 0; k < cLX[a]; ++k) t *= ux;
            for (int k = 0; k < cLY[a]; ++k) t *= uy;
            for (int k = 0; k < cLZ[a]; ++k) t *= uz;
            v = t;
        } else if (lane < 61) {                // edge channel encoding
            int t = lane - 52;
            v = embW[zmap(zs[snd]) * 3 + t / 3] * embW[zmap(zs[rcv]) * 3 + t % 3];
        }
        edata[(size_t)e * EDW + lane] = v;
        if (lane == 0) {
            int p = atomicAdd(&counts[rcv], 1);
            if (p < CAP) order[rcv * CAP + p] = e;
        }
    }
}

// ---------------- kernel 2: per-node accumulate (registers) + invariants ----------------
__global__ __launch_bounds__(256) void node_kernel(
    const float* __restrict__ edata, const int* __restrict__ counts,
    const int* __restrict__ order, float* __restrict__ out, int N)
{
    int n = blockIdx.x;
    if (n >= N) return;
    __shared__ float ed[4][EDW];          // 4 staged edge records
    __shared__ float A[NRBF * NA * NC];   // [s][a][c] = 1440 floats
    __shared__ float Bsh[NRBF * 8 * NC];  // [s][b][c] = 576 floats
    int tid = threadIdx.x;
    int deg = min(counts[n], CAP);

    // (s,a)-parallel accumulation: thread t<160 owns (s=t/20, a=t%20),
    // accumulates acc[c] += rad2[l(a),s]*ang[a]*enc[c] over edges.
    bool active = (tid < NRBF * NA);
    int s_i = tid / NA, a_i = tid % NA;
    int roff = active ? (cLOF[a_i] * 8 + s_i) : 0;   // rad2 slot in record
    int goff = 32 + a_i;                              // ang slot
    float acc[NC];
    #pragma unroll
    for (int c = 0; c < NC; ++c) acc[c] = 0.f;

    for (int j = 0; j < deg; j += 4) {
        int slot = tid >> 6, elem = tid & 63;
        if (j + slot < deg)
            ed[slot][elem] = edata[(size_t)order[n * CAP + j + slot] * EDW + elem];
        __syncthreads();
        int m_end = min(4, deg - j);
        for (int m = 0; m < m_end; ++m) {
            if (active) {
                float p = ed[m][roff] * ed[m][goff];
                #pragma unroll
                for (int c = 0; c < NC; ++c) acc[c] += p * ed[m][52 + c];
            }
        }
        __syncthreads();
    }

    if (active) {
        int base = (s_i * NA + a_i) * NC;
        #pragma unroll
        for (int c = 0; c < NC; ++c) A[base + c] = acc[c];
    }
    __syncthreads();

    // invariants: 72 threads, one (s,c) pair each
    if (tid < 72) {
        int s = tid / 9, c = tid % 9;
        float Av[NA];
        #pragma unroll
        for (int a = 0; a < NA; ++a) Av[a] = A[(s * NA + a) * NC + c];

        float b0 = Av[0];
        float b1 = Av[1]*Av[1] + Av[2]*Av[2] + Av[3]*Av[3];
        float b2 = Av[4]*Av[4] + 2.f*Av[5]*Av[5] + 2.f*Av[6]*Av[6]
                 + Av[7]*Av[7] + 2.f*Av[8]*Av[8] + Av[9]*Av[9];
        float b3 = Av[10]*Av[10] + 3.f*(Av[11]*Av[11] + Av[12]*Av[12] + Av[13]*Av[13])
                 + 6.f*Av[14]*Av[14] + 3.f*Av[15]*Av[15] + Av[16]*Av[16]
                 + 3.f*(Av[17]*Av[17] + Av[18]*Av[18]) + Av[19]*Av[19];
        float b4 = 0.f, b5 = 0.f, b6 = 0.f, b7 = 0.f;
        #pragma unroll
        for (int k = 0; k < NU3.n; ++k) {
            float term = NU3.pref[k] * Av[NU3.i1[k]] * Av[NU3.i2[k]] * Av[NU3.i3[k]];
            if      (NU3.cb[k] == 0) b4 += term;
            else if (NU3.cb[k] == 1) b5 += term;
            else if (NU3.cb[k] == 2) b6 += term;
            else                     b7 += term;
        }
        int sb = s * 8 * NC + c;
        Bsh[sb + 0*NC] = b0; Bsh[sb + 1*NC] = b1; Bsh[sb + 2*NC] = b2; Bsh[sb + 3*NC] = b3;
        Bsh[sb + 4*NC] = b4; Bsh[sb + 5*NC] = b5; Bsh[sb + 6*NC] = b6; Bsh[sb + 7*NC] = b7;
    }
    __syncthreads();
    float* op = out + (size_t)n * (NRBF * 8 * NC);
    for (int i = tid; i < NRBF * 8 * NC; i += 256) op[i] = Bsh[i];
}

// ---------------- launch ----------------
extern "C" void kernel_launch(void* const* d_in, const int* in_sizes, int n_in,
                              void* d_out, int out_size, void* d_ws, size_t ws_size,
                              hipStream_t stream) {
    const float* pos    = (const float*)d_in[0];
    const float* shifts = (const float*)d_in[1];
    const float* embW   = (const float*)d_in[2];
    const float* radW   = (const float*)d_in[3];
    const int*   zs     = (const int*)d_in[4];
    const int*   eidx   = (const int*)d_in[5];
    float* out = (float*)d_out;

    int N = in_sizes[0] / 3;   // positions [N,3]
    int E = in_sizes[5] / 2;   // edge_index [2,E]

    // workspace layout: edata [E*64 f32] | counts [N i32] | order [N*CAP i32]
    float* edata = (float*)d_ws;
    int* counts  = (int*)(edata + (size_t)E * EDW);
    int* order   = counts + N;

    hipMemsetAsync(counts, 0, (size_t)N * sizeof(int), stream);

    precompute_kernel<<<dim3((E + 3) / 4), dim3(256), 0, stream>>>(
        pos, shifts, embW, radW, zs, eidx, edata, counts, order, E);

    node_kernel<<<dim3(N), dim3(256), 0, stream>>>(edata, counts, order, out, N);
}

// Round 7
// 129.173 us; speedup vs baseline: 1.0443x; 1.0443x over previous
//
#include <hip/hip_runtime.h>

// ---------------- compile-time constants / tables ----------------
constexpr int NRBF = 8;   // radial basis functions
constexpr int NA   = 20;  // angular monomials (MAX_L=3)
constexpr int NC   = 9;   // edge channels (n_emb^2)
constexpr int EDW  = 64;  // per-edge record: 32 rad2 + 20 ang + 9 enc + 3 pad
constexpr int CAP  = 64;  // per-node edge bucket capacity (deg~Poisson(6))
constexpr int STG  = 16;  // edge records staged per round in node kernel

// monomial exponent tables, index order matches reference _lxlylz_list(3)
__constant__ int cLX[NA] = {0,1,0,0,2,1,1,0,0,0,3,2,2,1,1,1,0,0,0,0};
__constant__ int cLY[NA] = {0,0,1,0,0,1,0,2,1,0,0,1,0,2,1,0,3,2,1,0};
__constant__ int cLZ[NA] = {0,0,0,1,0,0,1,0,1,2,0,0,1,0,1,2,0,1,2,3};
__constant__ int cLOF[NA]= {0,1,1,1,2,2,2,2,2,2,3,3,3,3,3,3,3,3,3,3};
// host-side constexpr copy for compile-time register indexing
constexpr int kLOF[NA]  = {0,1,1,1,2,2,2,2,2,2,3,3,3,3,3,3,3,3,3,3};

__device__ __forceinline__ int zmap(int z) {
    return z == 1 ? 0 : (z == 6 ? 1 : (z == 7 ? 2 : 3));
}

// ---------------- nu=3 term table (constexpr-generated) ----------------
struct Nu3Tbl {
    int n;
    unsigned char i1[200], i2[200], i3[200], cb[200];
    float pref[200];
};
constexpr int idx_of(int lx, int ly, int lz) {
    int l = lx + ly + lz;
    int base = (l == 0) ? 0 : ((l == 1) ? 1 : ((l == 2) ? 4 : 10));
    int d = l - lx;
    return base + d * (d + 1) / 2 + (d - ly);
}
constexpr int factc(int k) { return k <= 1 ? 1 : k * factc(k - 1); }
constexpr float multinom(int lx, int ly, int lz) {
    return (float)(factc(lx + ly + lz) / (factc(lx) * factc(ly) * factc(lz)));
}
constexpr Nu3Tbl make_nu3() {
    Nu3Tbl t{};
    const int combos[4][3] = {{1,1,1},{1,1,2},{1,2,1},{2,1,1}};
    for (int q = 0; q < 4; ++q) {
        int e12 = combos[q][0], e13 = combos[q][1], e23 = combos[q][2];
        for (int ax = e12; ax >= 0; --ax) for (int ay = e12-ax; ay >= 0; --ay) { int az = e12-ax-ay;
        for (int bx = e13; bx >= 0; --bx) for (int by = e13-bx; by >= 0; --by) { int bz = e13-bx-by;
        for (int cx = e23; cx >= 0; --cx) for (int cy = e23-cx; cy >= 0; --cy) { int cz = e23-cx-cy;
            t.i1[t.n] = (unsigned char)idx_of(ax+bx, ay+by, az+bz);
            t.i2[t.n] = (unsigned char)idx_of(ax+cx, ay+cy, az+cz);
            t.i3[t.n] = (unsigned char)idx_of(bx+cx, by+cy, bz+cz);
            t.cb[t.n] = (unsigned char)q;
            t.pref[t.n] = multinom(ax,ay,az) * multinom(bx,by,bz) * multinom(cx,cy,cz);
            t.n++;
        }}}
    }
    return t;
}
constexpr Nu3Tbl NU3 = make_nu3();

// ---------------- kernel 1: per-edge compact record + direct bucketing ----------------
// 4 edges per 256-thread block (one wave64 per edge).
__global__ __launch_bounds__(256) void precompute_kernel(
    const float* __restrict__ pos, const float* __restrict__ shifts,
    const float* __restrict__ embW, const float* __restrict__ radW,
    const int* __restrict__ zs, const int* __restrict__ eidx,
    float* __restrict__ edata, int* __restrict__ counts, int* __restrict__ order,
    int E)
{
    __shared__ float s_rad[4][NRBF];
    int w = threadIdx.x >> 6;
    int lane = threadIdx.x & 63;
    int e = blockIdx.x * 4 + w;
    bool valid = (e < E);

    int snd = 0, rcv = 0;
    float dx = 0.f, dy = 0.f, dz = 0.f, len = 1.f;
    if (valid) {
        snd = eidx[e]; rcv = eidx[E + e];
        dx = pos[rcv*3+0] - pos[snd*3+0] + shifts[e*3+0];
        dy = pos[rcv*3+1] - pos[snd*3+1] + shifts[e*3+1];
        dz = pos[rcv*3+2] - pos[snd*3+2] + shifts[e*3+2];
        len = fmaxf(sqrtf(dx*dx + dy*dy + dz*dz), 1e-9f);
    }
    if (valid && lane < 8) {
        // Bessel RBF * polynomial cutoff (p=6): fc = 1 - 28 x^6 + 48 x^7 - 21 x^8
        float x = len * (1.0f / 5.5f);
        float fc = 0.f;
        if (x < 1.f) {
            float x2 = x * x, x6 = x2 * x2 * x2;
            fc = 1.f - 28.f * x6 + 48.f * x6 * x - 21.f * x6 * x2;
        }
        float rbf = 0.60302268915552724f *
                    sinf((float)(lane + 1) * 3.14159265358979323846f * len / 5.5f) / len;
        s_rad[w][lane] = rbf * fc;
    }
    __syncthreads();
    if (valid) {
        float v = 0.f;
        if (lane < 32) {                       // rad2[l][s] = sum_r W[l,r,s] * radial[r]
            int l = lane >> 3, s = lane & 7;
            float acc = 0.f;
            #pragma unroll
            for (int r = 0; r < 8; ++r) acc += radW[(l * 8 + r) * 8 + s] * s_rad[w][r];
            v = acc;
        } else if (lane < 52) {                // angular monomials
            int a = lane - 32;
            float inv = 1.f / len;
            float ux = dx * inv, uy = dy * inv, uz = dz * inv;
            float t = 1.f;
            for (int k = 0; k < cLX[a]; ++k) t *= ux;
            for (int k = 0; k < cLY[a]; ++k) t *= uy;
            for (int k = 0; k < cLZ[a]; ++k) t *= uz;
            v = t;
        } else if (lane < 61) {                // edge channel encoding
            int t = lane - 52;
            v = embW[zmap(zs[snd]) * 3 + t / 3] * embW[zmap(zs[rcv]) * 3 + t % 3];
        }
        edata[(size_t)e * EDW + lane] = v;
        if (lane == 0) {
            int p = atomicAdd(&counts[rcv], 1);
            if (p < CAP) order[rcv * CAP + p] = e;
        }
    }
}

// ---------------- kernel 2: per-node register accumulate + invariants ----------------
// One node per 128-thread block. Threads 0..71 own (s,c) and keep all 20
// A[a] in registers; invariants computed register-local (no LDS A tensor).
__global__ __launch_bounds__(128) void node_kernel(
    const float* __restrict__ edata, const int* __restrict__ counts,
    const int* __restrict__ order, float* __restrict__ out, int N)
{
    int n = blockIdx.x;
    if (n >= N) return;
    __shared__ float ed[STG][EDW];        // staged edge records (4 KB)
    __shared__ int   sidx[STG];
    __shared__ float Bsh[NRBF * 8 * NC];  // [s][b][c] = 576 floats
    int tid = threadIdx.x;
    int deg = min(counts[n], CAP);

    bool active = (tid < NRBF * NC);      // 72 (s,c) threads
    int s_i = tid / NC, c_i = tid % NC;

    float Av[NA];
    #pragma unroll
    for (int a = 0; a < NA; ++a) Av[a] = 0.f;

    for (int base = 0; base < deg; base += STG) {
        int nb = min(STG, deg - base);
        if (tid < nb) sidx[tid] = order[n * CAP + base + tid];
        __syncthreads();
        for (int i = tid; i < nb * EDW; i += 128)
            ed[i >> 6][i & 63] = edata[(size_t)sidx[i >> 6] * EDW + (i & 63)];
        __syncthreads();
        if (active) {
            for (int m = 0; m < nb; ++m) {
                float ec = ed[m][52 + c_i];
                float rl[4];
                rl[0] = ed[m][ 0 + s_i] * ec;
                rl[1] = ed[m][ 8 + s_i] * ec;
                rl[2] = ed[m][16 + s_i] * ec;
                rl[3] = ed[m][24 + s_i] * ec;
                #pragma unroll
                for (int a = 0; a < NA; ++a)
                    Av[a] += rl[kLOF[a]] * ed[m][32 + a];
            }
        }
        __syncthreads();
    }

    if (active) {
        float b0 = Av[0];
        float b1 = Av[1]*Av[1] + Av[2]*Av[2] + Av[3]*Av[3];
        float b2 = Av[4]*Av[4] + 2.f*Av[5]*Av[5] + 2.f*Av[6]*Av[6]
                 + Av[7]*Av[7] + 2.f*Av[8]*Av[8] + Av[9]*Av[9];
        float b3 = Av[10]*Av[10] + 3.f*(Av[11]*Av[11] + Av[12]*Av[12] + Av[13]*Av[13])
                 + 6.f*Av[14]*Av[14] + 3.f*Av[15]*Av[15] + Av[16]*Av[16]
                 + 3.f*(Av[17]*Av[17] + Av[18]*Av[18]) + Av[19]*Av[19];
        float b4 = 0.f, b5 = 0.f, b6 = 0.f, b7 = 0.f;
        #pragma unroll
        for (int k = 0; k < NU3.n; ++k) {
            float term = NU3.pref[k] * Av[NU3.i1[k]] * Av[NU3.i2[k]] * Av[NU3.i3[k]];
            if      (NU3.cb[k] == 0) b4 += term;
            else if (NU3.cb[k] == 1) b5 += term;
            else if (NU3.cb[k] == 2) b6 += term;
            else                     b7 += term;
        }
        int sb = s_i * 8 * NC + c_i;
        Bsh[sb + 0*NC] = b0; Bsh[sb + 1*NC] = b1; Bsh[sb + 2*NC] = b2; Bsh[sb + 3*NC] = b3;
        Bsh[sb + 4*NC] = b4; Bsh[sb + 5*NC] = b5; Bsh[sb + 6*NC] = b6; Bsh[sb + 7*NC] = b7;
    }
    __syncthreads();
    float* op = out + (size_t)n * (NRBF * 8 * NC);
    for (int i = tid; i < NRBF * 8 * NC; i += 128) op[i] = Bsh[i];
}

// ---------------- launch ----------------
extern "C" void kernel_launch(void* const* d_in, const int* in_sizes, int n_in,
                              void* d_out, int out_size, void* d_ws, size_t ws_size,
                              hipStream_t stream) {
    const float* pos    = (const float*)d_in[0];
    const float* shifts = (const float*)d_in[1];
    const float* embW   = (const float*)d_in[2];
    const float* radW   = (const float*)d_in[3];
    const int*   zs     = (const int*)d_in[4];
    const int*   eidx   = (const int*)d_in[5];
    float* out = (float*)d_out;

    int N = in_sizes[0] / 3;   // positions [N,3]
    int E = in_sizes[5] / 2;   // edge_index [2,E]

    // workspace layout: edata [E*64 f32] | counts [N i32] | order [N*CAP i32]
    float* edata = (float*)d_ws;
    int* counts  = (int*)(edata + (size_t)E * EDW);
    int* order   = counts + N;

    hipMemsetAsync(counts, 0, (size_t)N * sizeof(int), stream);

    precompute_kernel<<<dim3((E + 3) / 4), dim3(256), 0, stream>>>(
        pos, shifts, embW, radW, zs, eidx, edata, counts, order, E);

    node_kernel<<<dim3(N), dim3(128), 0, stream>>>(edata, counts, order, out, N);
}